// Round 7
// baseline (246.298 us; speedup 1.0000x reference)
//
#include <hip/hip_runtime.h>
#include <hip/hip_bf16.h>
#include <math.h>

// Problem constants
#define BB 2
#define SS 2048
#define DD 512
#define HH 8
#define HD 64
#define LN_EPS 1e-5f

typedef _Float16 f16;
typedef f16 half8 __attribute__((ext_vector_type(8)));
typedef f16 half4 __attribute__((ext_vector_type(4)));
typedef __fp16 fp16x2 __attribute__((ext_vector_type(2)));

typedef float f32x4 __attribute__((ext_vector_type(4)));

// packed fp32->f16 conversion (v_cvt_pkrtz_f16_f32): 2 elems / instr
__device__ __forceinline__ half4 cvt4(const float4 v) {
    const fp16x2 p0 = __builtin_amdgcn_cvt_pkrtz(v.x, v.y);
    const fp16x2 p1 = __builtin_amdgcn_cvt_pkrtz(v.z, v.w);
    half4 h;
    h.x = (f16)p0.x; h.y = (f16)p0.y; h.z = (f16)p1.x; h.w = (f16)p1.y;
    return h;
}

// ---------------------------------------------------------------------------
// Fused QKV projection GEMM (f16 MFMA, fp32 accumulate).
//   y[m,n] = dot(A[m,:], W[n,:]) + bias[n]    (torch Linear: dot of rows)
// grid (8, 32, 3): z selects {Q,K,V}.  Tile 128(M)x64(N), BK=64,
// 128 threads = 2 waves, each wave a 64x64 sub-tile.
// z=0,1 -> f16 head-split [B,H,S,HD];  z=2 -> f16 transposed [B,H,HD,S].
// ---------------------------------------------------------------------------
__global__ __launch_bounds__(128) void gemm_qkv(
    const float* __restrict__ qin, const float* __restrict__ kin,
    const float* __restrict__ vin,
    const float* __restrict__ wq, const float* __restrict__ wk,
    const float* __restrict__ wv,
    const float* __restrict__ bq, const float* __restrict__ bk,
    const float* __restrict__ bv,
    f16* __restrict__ Qh, f16* __restrict__ Kh, f16* __restrict__ Vt) {
    __shared__ f16 As[128][72];  // 144B rows: 16B-aligned, 2-way bank alias (free)
    __shared__ f16 Bs[64][72];

    const int z = blockIdx.z;
    const float* A;  const float* W;  const float* bias;  f16* out;
    if (z == 0)      { A = qin; W = wq; bias = bq; out = Qh; }
    else if (z == 1) { A = kin; W = wk; bias = bk; out = Kh; }
    else             { A = vin; W = wv; bias = bv; out = Vt; }

    const int tid = threadIdx.x;
    const int lane = tid & 63;
    const int wid = tid >> 6;        // 0..1 (M direction)
    const int m0 = blockIdx.y * 128;
    const int n0 = blockIdx.x * 64;

    const int lr = tid >> 4;         // 0..7 staging row
    const int lc = (tid & 15) * 4;   // staging col (fp32 units)

    const int cl = lane & 15;
    const int g  = lane >> 4;        // 0..3

    f32x4 acc[4][4] = {};

    for (int k0 = 0; k0 < DD; k0 += 64) {
#pragma unroll
        for (int p = 0; p < 16; ++p) {
            const int r = p * 8 + lr;
            const float4 v = *reinterpret_cast<const float4*>(A + (size_t)(m0 + r) * DD + k0 + lc);
            *reinterpret_cast<half4*>(&As[r][lc]) = cvt4(v);
        }
#pragma unroll
        for (int p = 0; p < 8; ++p) {
            const int r = p * 8 + lr;
            const float4 v = *reinterpret_cast<const float4*>(W + (size_t)(n0 + r) * DD + k0 + lc);
            *reinterpret_cast<half4*>(&Bs[r][lc]) = cvt4(v);
        }
        __syncthreads();

#pragma unroll
        for (int ks = 0; ks < 2; ++ks) {
            const int co = ks * 32 + g * 8;
            half8 a[4], b[4];
#pragma unroll
            for (int i = 0; i < 4; ++i)
                a[i] = *reinterpret_cast<const half8*>(&As[wid * 64 + i * 16 + cl][co]);
#pragma unroll
            for (int j = 0; j < 4; ++j)
                b[j] = *reinterpret_cast<const half8*>(&Bs[j * 16 + cl][co]);
#pragma unroll
            for (int i = 0; i < 4; ++i)
#pragma unroll
                for (int j = 0; j < 4; ++j)
                    acc[i][j] = __builtin_amdgcn_mfma_f32_16x16x32_f16(a[i], b[j], acc[i][j], 0, 0, 0);
        }
        __syncthreads();
    }

    // epilogue (m89-verified D-frag: col=cl, row=g*4+r). n-tile == head size.
    const int h = n0 >> 6;
#pragma unroll
    for (int i = 0; i < 4; ++i) {
#pragma unroll
        for (int r = 0; r < 4; ++r) {
            const int m = m0 + wid * 64 + i * 16 + g * 4 + r;
            const int b = m >> 11;         // / SS
            const int s = m & (SS - 1);
#pragma unroll
            for (int j = 0; j < 4; ++j) {
                const int n = n0 + j * 16 + cl;
                const f16 y = (f16)(acc[i][j][r] + bias[n]);
                if (z == 2)
                    out[(((size_t)b * HH + h) * HD + (n & 63)) * SS + s] = y;  // [B,H,HD,S]
                else
                    out[(((size_t)b * HH + h) * SS + s) * HD + (n & 63)] = y;  // [B,H,S,HD]
            }
        }
    }
}

// ---------------------------------------------------------------------------
// Flash attention, f16 MFMA, causal, K/V LDS-staged.
// grid (32 q-tiles, 16 bh), block 256 = 4 waves; wave w owns q-rows
// [qt*64 + w*16, +16).  KVBLK = 128.
// Rationale: per-wave global K/V fragment loads would be read 4x per block
// (one per wave) -> ~1.08 GB L2 demand ≈ 31 µs at the 34.5 TB/s L2 ceiling,
// vs ~4 µs of MFMA. Cooperative LDS staging cuts that 4x.
// LDS rows are 16B-multiples; all b128 reads/writes land at exactly
// 8 lanes per 16B slot (the wave64 minimum -> conflict-free).
// ---------------------------------------------------------------------------
__global__ __launch_bounds__(256) void flash_f16(const f16* __restrict__ Qh,
                                                 const f16* __restrict__ Kh,
                                                 const f16* __restrict__ Vt,
                                                 float* __restrict__ Oc) {
    __shared__ f16 Ks[128][72];     // [kv][d]   144B rows
    __shared__ f16 Vs[64][136];     // [d][kv]   272B rows
    __shared__ f16 Ps[4][16][136];  // per-wave P tile; 272B rows

    const int tid = threadIdx.x;
    const int lane = tid & 63;
    const int w = tid >> 6;
    const int qt = blockIdx.x;
    const int bh = blockIdx.y;
    const int cl = lane & 15;
    const int g  = lane >> 4;

    const f16* Qb = Qh + (size_t)bh * SS * HD;
    const f16* Kb = Kh + (size_t)bh * SS * HD;
    const f16* Vb = Vt + (size_t)bh * HD * SS;

    const int q0w = qt * 64 + w * 16;

    // Q fragments, pre-scaled by 1/8 * log2(e) so softmax runs in exp2 domain.
    const f16 qsc = (f16)(0.125f * 1.44269504088896f);
    half8 aq[2];
#pragma unroll
    for (int ks = 0; ks < 2; ++ks) {
        half8 t = *reinterpret_cast<const half8*>(Qb + (size_t)(q0w + cl) * HD + ks * 32 + g * 8);
#pragma unroll
        for (int e = 0; e < 8; ++e) t[e] = t[e] * qsc;
        aq[ks] = t;
    }

    f32x4 ctx[4] = {};
    float m_i[4], l_i[4];
#pragma unroll
    for (int r = 0; r < 4; ++r) { m_i[r] = -INFINITY; l_i[r] = 0.f; }

    const int nfull = (qt * 64) >> 7;  // # of full (unmasked) 128-wide KV tiles

    for (int kt = 0; kt <= nfull; ++kt) {
        const int kvb = kt * 128;
        const bool diag = (kt == nfull);

        // ---- cooperative stage: K tile 128x64 -> Ks, V tile 64x128 -> Vs ----
        // 1024 chunks of 8 f16 each; 256 threads x 4. Global reads coalesced
        // (8/16 consecutive threads cover one full row).
#pragma unroll
        for (int i = 0; i < 4; ++i) {
            const int c = tid + 256 * i;
            const int kr = c >> 3;            // 0..127
            const int kc = (c & 7) * 8;       // f16 col in [0,64)
            *reinterpret_cast<half8*>(&Ks[kr][kc]) =
                *reinterpret_cast<const half8*>(Kb + (size_t)(kvb + kr) * HD + kc);
            const int vr = c >> 4;            // 0..63
            const int vc = (c & 15) * 8;      // f16 col in [0,128)
            *reinterpret_cast<half8*>(&Vs[vr][vc]) =
                *reinterpret_cast<const half8*>(Vb + (size_t)vr * SS + kvb + vc);
        }
        __syncthreads();

        // S^log2 = (Q*qsc) K^T   -> 16 MFMA, K from LDS
        f32x4 s[8] = {};
#pragma unroll
        for (int ks = 0; ks < 2; ++ks) {
#pragma unroll
            for (int j = 0; j < 8; ++j) {
                const half8 bk = *reinterpret_cast<const half8*>(&Ks[j * 16 + cl][ks * 32 + g * 8]);
                s[j] = __builtin_amdgcn_mfma_f32_16x16x32_f16(aq[ks], bk, s[j], 0, 0, 0);
            }
        }

        if (diag) {
#pragma unroll
            for (int j = 0; j < 8; ++j)
#pragma unroll
                for (int r = 0; r < 4; ++r)
                    if (kvb + j * 16 + cl > q0w + g * 4 + r) s[j][r] = -INFINITY;
        }

        // online softmax in exp2 domain; row-reduce over 16-lane groups
#pragma unroll
        for (int r = 0; r < 4; ++r) {
            float mx = s[0][r];
#pragma unroll
            for (int j = 1; j < 8; ++j) mx = fmaxf(mx, s[j][r]);
#pragma unroll
            for (int off = 1; off < 16; off <<= 1) mx = fmaxf(mx, __shfl_xor(mx, off, 16));
            const float newm = fmaxf(m_i[r], mx);
            const float fac = exp2f(m_i[r] - newm);
            float rs = 0.f;
#pragma unroll
            for (int j = 0; j < 8; ++j) {
                const float p = exp2f(s[j][r] - newm);
                s[j][r] = p;
                rs += p;
            }
#pragma unroll
            for (int off = 1; off < 16; off <<= 1) rs += __shfl_xor(rs, off, 16);
            l_i[r] = l_i[r] * fac + rs;
            m_i[r] = newm;
#pragma unroll
            for (int j = 0; j < 4; ++j) ctx[j][r] *= fac;
        }

        // P (D-frag) -> per-wave LDS -> A-frag
#pragma unroll
        for (int j = 0; j < 8; ++j)
#pragma unroll
            for (int r = 0; r < 4; ++r)
                Ps[w][g * 4 + r][j * 16 + cl] = (f16)s[j][r];

        half8 ap[4];
#pragma unroll
        for (int ks = 0; ks < 4; ++ks)
            ap[ks] = *reinterpret_cast<const half8*>(&Ps[w][cl][ks * 32 + g * 8]);

        // ctx += P V   -> 16 MFMA, V from LDS
#pragma unroll
        for (int ks = 0; ks < 4; ++ks) {
#pragma unroll
            for (int j = 0; j < 4; ++j) {
                const half8 bv = *reinterpret_cast<const half8*>(&Vs[j * 16 + cl][ks * 32 + g * 8]);
                ctx[j] = __builtin_amdgcn_mfma_f32_16x16x32_f16(ap[ks], bv, ctx[j], 0, 0, 0);
            }
        }
        __syncthreads();  // protect Ks/Vs before next iteration's staging
    }

    // epilogue: merged heads, fp32
    const int b = bh >> 3;
    const int h = bh & (HH - 1);
#pragma unroll
    for (int r = 0; r < 4; ++r) {
        const float inv = 1.0f / l_i[r];
        const int qg = q0w + g * 4 + r;
#pragma unroll
        for (int j = 0; j < 4; ++j)
            Oc[((size_t)b * SS + qg) * DD + h * HD + j * 16 + cl] = ctx[j][r] * inv;
    }
}

// ---------------------------------------------------------------------------
// O-projection GEMM + residual (f16 MFMA, fp32 out): X = Oc @ wo.T + bo + resid
// ---------------------------------------------------------------------------
__global__ __launch_bounds__(128) void gemm_o(const float* __restrict__ A,
                                              const float* __restrict__ W,
                                              const float* __restrict__ bias,
                                              const float* __restrict__ resid,
                                              float* __restrict__ out) {
    __shared__ f16 As[128][72];
    __shared__ f16 Bs[64][72];

    const int tid = threadIdx.x;
    const int lane = tid & 63;
    const int wid = tid >> 6;
    const int m0 = blockIdx.y * 128;
    const int n0 = blockIdx.x * 64;
    const int lr = tid >> 4;
    const int lc = (tid & 15) * 4;
    const int cl = lane & 15;
    const int g  = lane >> 4;

    f32x4 acc[4][4] = {};

    for (int k0 = 0; k0 < DD; k0 += 64) {
#pragma unroll
        for (int p = 0; p < 16; ++p) {
            const int r = p * 8 + lr;
            const float4 v = *reinterpret_cast<const float4*>(A + (size_t)(m0 + r) * DD + k0 + lc);
            *reinterpret_cast<half4*>(&As[r][lc]) = cvt4(v);
        }
#pragma unroll
        for (int p = 0; p < 8; ++p) {
            const int r = p * 8 + lr;
            const float4 v = *reinterpret_cast<const float4*>(W + (size_t)(n0 + r) * DD + k0 + lc);
            *reinterpret_cast<half4*>(&Bs[r][lc]) = cvt4(v);
        }
        __syncthreads();

#pragma unroll
        for (int ks = 0; ks < 2; ++ks) {
            const int co = ks * 32 + g * 8;
            half8 a[4], b[4];
#pragma unroll
            for (int i = 0; i < 4; ++i)
                a[i] = *reinterpret_cast<const half8*>(&As[wid * 64 + i * 16 + cl][co]);
#pragma unroll
            for (int j = 0; j < 4; ++j)
                b[j] = *reinterpret_cast<const half8*>(&Bs[j * 16 + cl][co]);
#pragma unroll
            for (int i = 0; i < 4; ++i)
#pragma unroll
                for (int j = 0; j < 4; ++j)
                    acc[i][j] = __builtin_amdgcn_mfma_f32_16x16x32_f16(a[i], b[j], acc[i][j], 0, 0, 0);
        }
        __syncthreads();
    }

#pragma unroll
    for (int i = 0; i < 4; ++i) {
#pragma unroll
        for (int r = 0; r < 4; ++r) {
            const int m = m0 + wid * 64 + i * 16 + g * 4 + r;
#pragma unroll
            for (int j = 0; j < 4; ++j) {
                const int n = n0 + j * 16 + cl;
                const size_t idx = (size_t)m * DD + n;
                out[idx] = acc[i][j][r] + bias[n] + resid[idx];
            }
        }
    }
}

// ---------------------------------------------------------------------------
// LayerNorm: one wave per row of 512, fp32.
// ---------------------------------------------------------------------------
__global__ __launch_bounds__(256) void ln_k(const float* __restrict__ X,
                                            const float* __restrict__ gamma,
                                            const float* __restrict__ beta,
                                            float* __restrict__ out) {
    const int row = blockIdx.x * 4 + (threadIdx.x >> 6);
    const int lane = threadIdx.x & 63;
    const float* x = X + (size_t)row * DD;

    const float4 v0 = *reinterpret_cast<const float4*>(x + lane * 4);
    const float4 v1 = *reinterpret_cast<const float4*>(x + 256 + lane * 4);

    float sum = v0.x + v0.y + v0.z + v0.w + v1.x + v1.y + v1.z + v1.w;
#pragma unroll
    for (int off = 1; off < 64; off <<= 1) sum += __shfl_xor(sum, off, 64);
    const float mu = sum * (1.0f / DD);

    const float d0[8] = {v0.x - mu, v0.y - mu, v0.z - mu, v0.w - mu,
                         v1.x - mu, v1.y - mu, v1.z - mu, v1.w - mu};
    float vs = 0.f;
#pragma unroll
    for (int t = 0; t < 8; ++t) vs += d0[t] * d0[t];
#pragma unroll
    for (int off = 1; off < 64; off <<= 1) vs += __shfl_xor(vs, off, 64);
    const float rstd = rsqrtf(vs * (1.0f / DD) + LN_EPS);

    const float4 g0 = *reinterpret_cast<const float4*>(gamma + lane * 4);
    const float4 g1 = *reinterpret_cast<const float4*>(gamma + 256 + lane * 4);
    const float4 b0 = *reinterpret_cast<const float4*>(beta + lane * 4);
    const float4 b1 = *reinterpret_cast<const float4*>(beta + 256 + lane * 4);

    float4 o0, o1;
    o0.x = g0.x * d0[0] * rstd + b0.x;
    o0.y = g0.y * d0[1] * rstd + b0.y;
    o0.z = g0.z * d0[2] * rstd + b0.z;
    o0.w = g0.w * d0[3] * rstd + b0.w;
    o1.x = g1.x * d0[4] * rstd + b1.x;
    o1.y = g1.y * d0[5] * rstd + b1.y;
    o1.z = g1.z * d0[6] * rstd + b1.z;
    o1.w = g1.w * d0[7] * rstd + b1.w;

    *reinterpret_cast<float4*>(out + (size_t)row * DD + lane * 4) = o0;
    *reinterpret_cast<float4*>(out + (size_t)row * DD + 256 + lane * 4) = o1;
}

// ---------------------------------------------------------------------------
extern "C" void kernel_launch(void* const* d_in, const int* in_sizes, int n_in,
                              void* d_out, int out_size, void* d_ws, size_t ws_size,
                              hipStream_t stream) {
    const float* q     = (const float*)d_in[0];
    const float* k     = (const float*)d_in[1];
    const float* v     = (const float*)d_in[2];
    const float* wq    = (const float*)d_in[3];
    const float* bq    = (const float*)d_in[4];
    const float* wk    = (const float*)d_in[5];
    const float* bk    = (const float*)d_in[6];
    const float* wv    = (const float*)d_in[7];
    const float* bv    = (const float*)d_in[8];
    const float* wo    = (const float*)d_in[9];
    const float* bo    = (const float*)d_in[10];
    const float* gamma = (const float*)d_in[11];
    const float* beta  = (const float*)d_in[12];
    // d_in[13] = causal mask — structure known, not read.

    // ws layout (20 MB): Qh 0-4, Kh 4-8, Vt 8-12 (f16), Oc 12-20 (fp32),
    // X aliases 0-8 (Qh/Kh dead once gemm_o runs).
    char* ws = (char*)d_ws;
    f16*   Qh = (f16*)(ws);
    f16*   Kh = (f16*)(ws + (4u << 20));
    f16*   Vt = (f16*)(ws + (8u << 20));
    float* Oc = (float*)(ws + (12u << 20));
    float* X  = (float*)(ws);

    gemm_qkv<<<dim3(DD / 64, (BB * SS) / 128, 3), 128, 0, stream>>>(
        q, k, v, wq, wk, wv, bq, bk, bv, Qh, Kh, Vt);

    flash_f16<<<dim3(SS / 64, BB * HH), 256, 0, stream>>>(Qh, Kh, Vt, Oc);

    gemm_o<<<dim3(DD / 64, (BB * SS) / 128), 128, 0, stream>>>(Oc, wo, bo, q, X);

    ln_k<<<(BB * SS) / 4, 256, 0, stream>>>(X, gamma, beta, (float*)d_out);
}

// Round 10
// 212.810 us; speedup vs baseline: 1.1574x; 1.1574x over previous
//
#include <hip/hip_runtime.h>
#include <hip/hip_bf16.h>
#include <math.h>

// Problem constants
#define BB 2
#define SS 2048
#define DD 512
#define HH 8
#define HD 64
#define LN_EPS 1e-5f

typedef _Float16 f16;
typedef f16 half8 __attribute__((ext_vector_type(8)));
typedef f16 half4 __attribute__((ext_vector_type(4)));
typedef __fp16 fp16x2 __attribute__((ext_vector_type(2)));
typedef float f32x4 __attribute__((ext_vector_type(4)));

// packed fp32->f16 conversion (v_cvt_pkrtz_f16_f32)
__device__ __forceinline__ half4 cvt4(const float4 v) {
    const fp16x2 p0 = __builtin_amdgcn_cvt_pkrtz(v.x, v.y);
    const fp16x2 p1 = __builtin_amdgcn_cvt_pkrtz(v.z, v.w);
    half4 h;
    h.x = (f16)p0.x; h.y = (f16)p0.y; h.z = (f16)p1.x; h.w = (f16)p1.y;
    return h;
}

// ---------------------------------------------------------------------------
// K0: one-shot weight fp32->f16 (removes 32x-redundant per-tile cvt in GEMMs)
// ---------------------------------------------------------------------------
__global__ __launch_bounds__(256) void cvt_w(const float* __restrict__ a, const float* __restrict__ b,
                                             const float* __restrict__ c, const float* __restrict__ d,
                                             f16* __restrict__ oa, f16* __restrict__ ob,
                                             f16* __restrict__ oc, f16* __restrict__ od) {
    const int i = blockIdx.x * 256 + threadIdx.x;  // 0..65535 (512*512/4)
    ((half4*)oa)[i] = cvt4(((const float4*)a)[i]);
    ((half4*)ob)[i] = cvt4(((const float4*)b)[i]);
    ((half4*)oc)[i] = cvt4(((const float4*)c)[i]);
    ((half4*)od)[i] = cvt4(((const float4*)d)[i]);
}

// ---------------------------------------------------------------------------
// K1: fused QKV projection. Tile 128M x 128N, BK=64, 256 thr = 4 waves (2x2),
// each wave 64x64. A fp32 (cvt on stage), W f16 (pure copy).
// grid (4, 32, 3). z=0,1 -> f16 [B,H,S,HD]; z=2 -> f16 [B,H,HD,S].
// ---------------------------------------------------------------------------
__global__ __launch_bounds__(256) void gemm_qkv(
    const float* __restrict__ qin, const float* __restrict__ kin,
    const float* __restrict__ vin,
    const f16* __restrict__ wqf, const f16* __restrict__ wkf,
    const f16* __restrict__ wvf,
    const float* __restrict__ bq, const float* __restrict__ bk,
    const float* __restrict__ bv,
    f16* __restrict__ Qh, f16* __restrict__ Kh, f16* __restrict__ Vt) {
    __shared__ f16 As[128][72];
    __shared__ f16 Bs[128][72];

    const int z = blockIdx.z;
    const float* A; const f16* W; const float* bias; f16* out;
    if (z == 0)      { A = qin; W = wqf; bias = bq; out = Qh; }
    else if (z == 1) { A = kin; W = wkf; bias = bk; out = Kh; }
    else             { A = vin; W = wvf; bias = bv; out = Vt; }

    const int tid = threadIdx.x;
    const int lane = tid & 63;
    const int wid = tid >> 6;
    const int wr = wid >> 1, wc = wid & 1;
    const int cl = lane & 15, g = lane >> 4;
    const int m0 = blockIdx.y * 128, n0 = blockIdx.x * 128;
    const int srow = tid >> 1, scp = tid & 1;  // staging: row 0..127, col-half

    f32x4 acc[4][4] = {};

    for (int k0 = 0; k0 < DD; k0 += 64) {
#pragma unroll
        for (int p = 0; p < 4; ++p) {
            const float* src = A + (size_t)(m0 + srow) * DD + k0 + scp * 32 + p * 8;
            const half4 lo = cvt4(*(const float4*)src);
            const half4 hi = cvt4(*(const float4*)(src + 4));
            half8 h;
            h[0]=lo.x; h[1]=lo.y; h[2]=lo.z; h[3]=lo.w;
            h[4]=hi.x; h[5]=hi.y; h[6]=hi.z; h[7]=hi.w;
            *(half8*)&As[srow][scp * 32 + p * 8] = h;
        }
#pragma unroll
        for (int p = 0; p < 4; ++p)
            *(half8*)&Bs[srow][scp * 32 + p * 8] =
                *(const half8*)(W + (size_t)(n0 + srow) * DD + k0 + scp * 32 + p * 8);
        __syncthreads();

#pragma unroll
        for (int ks = 0; ks < 2; ++ks) {
            half8 a[4], b[4];
#pragma unroll
            for (int i = 0; i < 4; ++i)
                a[i] = *(const half8*)&As[wr * 64 + i * 16 + cl][ks * 32 + g * 8];
#pragma unroll
            for (int j = 0; j < 4; ++j)
                b[j] = *(const half8*)&Bs[wc * 64 + j * 16 + cl][ks * 32 + g * 8];
#pragma unroll
            for (int i = 0; i < 4; ++i)
#pragma unroll
                for (int j = 0; j < 4; ++j)
                    acc[i][j] = __builtin_amdgcn_mfma_f32_16x16x32_f16(a[i], b[j], acc[i][j], 0, 0, 0);
        }
        __syncthreads();
    }

    // epilogue: D-frag col=cl, row=g*4+r
#pragma unroll
    for (int j = 0; j < 4; ++j) {
        const int n = n0 + wc * 64 + j * 16 + cl;
        const int h = n >> 6, d = n & 63;
        const float bn = bias[n];
#pragma unroll
        for (int i = 0; i < 4; ++i) {
#pragma unroll
            for (int r = 0; r < 4; ++r) {
                const int m = m0 + wr * 64 + i * 16 + g * 4 + r;
                const int b = m >> 11, s = m & (SS - 1);
                const f16 y = (f16)(acc[i][j][r] + bn);
                if (z == 2) out[(((size_t)b * HH + h) * HD + d) * SS + s] = y;
                else        out[(((size_t)b * HH + h) * SS + s) * HD + d] = y;
            }
        }
    }
}

// ---------------------------------------------------------------------------
// K2: flash attention, SWAPPED-operand MFMA (lane owns one q-row), causal.
// grid (32 qt, 16 bh), 256 thr = 4 waves; wave w: q-rows qt*64+w*16..+16.
// KVBLK=128. T14 reg-prefetch staging. Softmax: 31 reg-fmax + 2 shfl_xor.
// s[j][r]: kv = kvb + j*16 + g*4 + r, q = q0w + cl.
// ctxT[jj][r]: d = jj*16 + g*4 + r, q = q0w + cl.
// PV contraction: kv=128 -> 4 k-segments (ks<4).
// ---------------------------------------------------------------------------
__global__ __launch_bounds__(256) void flash_f16(const f16* __restrict__ Qh,
                                                 const f16* __restrict__ Kh,
                                                 const f16* __restrict__ Vt,
                                                 f16* __restrict__ Of) {
    __shared__ f16 Ks[128][72];     // [kv][d]
    __shared__ f16 Vs[64][136];     // [d][kv]
    __shared__ f16 Ps[4][16][136];  // per-wave [q 0..15][kv 0..127]

    const int tid = threadIdx.x;
    const int lane = tid & 63;
    const int w = tid >> 6;
    const int qt = blockIdx.x;
    const int bh = blockIdx.y;
    const int cl = lane & 15, g = lane >> 4;

    const f16* Qb = Qh + (size_t)bh * SS * HD;
    const f16* Kb = Kh + (size_t)bh * SS * HD;
    const f16* Vb = Vt + (size_t)bh * HD * SS;

    const int q0w = qt * 64 + w * 16;
    const int qlane = q0w + cl;  // this lane's q-row

    // Q fragment (B-operand), pre-scaled by 1/8*log2(e) for exp2-domain softmax
    const f16 qsc = (f16)(0.125f * 1.44269504088896f);
    half8 bq[2];
#pragma unroll
    for (int ks = 0; ks < 2; ++ks) {
        half8 t = *(const half8*)(Qb + (size_t)qlane * HD + ks * 32 + g * 8);
#pragma unroll
        for (int e = 0; e < 8; ++e) t[e] = t[e] * qsc;
        bq[ks] = t;
    }

    f32x4 ctxT[4] = {};
    float m_s = -INFINITY, l_s = 0.f;

    const int nfull = (qt * 64) >> 7;

    // T14 prefetch registers + stage macros
    half8 kreg[4], vreg[4];
#define LOADT(KT)                                                                     \
    {                                                                                 \
        const int kvbase = (KT) * 128;                                                \
        _Pragma("unroll") for (int i2 = 0; i2 < 4; ++i2) {                            \
            const int c = tid + 256 * i2;                                             \
            kreg[i2] = *(const half8*)(Kb + (size_t)(kvbase + (c >> 3)) * HD + (c & 7) * 8); \
            vreg[i2] = *(const half8*)(Vb + (size_t)(c >> 4) * SS + kvbase + (c & 15) * 8);  \
        }                                                                             \
    }
#define WRITET()                                                                      \
    {                                                                                 \
        _Pragma("unroll") for (int i2 = 0; i2 < 4; ++i2) {                            \
            const int c = tid + 256 * i2;                                             \
            *(half8*)&Ks[c >> 3][(c & 7) * 8] = kreg[i2];                             \
            *(half8*)&Vs[c >> 4][(c & 15) * 8] = vreg[i2];                            \
        }                                                                             \
    }

    LOADT(0);
    WRITET();
    __syncthreads();

    for (int kt = 0; kt <= nfull; ++kt) {
        const int kvb = kt * 128;
        const bool diag = (kt == nfull);

        if (kt < nfull) LOADT(kt + 1);  // hide global latency under compute

        // S^T = K Q^T (swapped): contraction d=64 -> 2 k-segments
        f32x4 s[8] = {};
#pragma unroll
        for (int ks = 0; ks < 2; ++ks) {
#pragma unroll
            for (int j = 0; j < 8; ++j) {
                const half8 ak = *(const half8*)&Ks[j * 16 + cl][ks * 32 + g * 8];
                s[j] = __builtin_amdgcn_mfma_f32_16x16x32_f16(ak, bq[ks], s[j], 0, 0, 0);
            }
        }

        if (diag) {
#pragma unroll
            for (int j = 0; j < 8; ++j) {
                const int kvj = kvb + j * 16 + g * 4;
#pragma unroll
                for (int r = 0; r < 4; ++r)
                    if (kvj + r > qlane) s[j][r] = -INFINITY;
            }
        }

        // softmax: in-register row max/sum + 2 shuffles (lanes cl+{0,16,32,48})
        float mx = -INFINITY;
#pragma unroll
        for (int j = 0; j < 8; ++j)
            mx = fmaxf(mx, fmaxf(fmaxf(s[j][0], s[j][1]), fmaxf(s[j][2], s[j][3])));
        mx = fmaxf(mx, __shfl_xor(mx, 16));
        mx = fmaxf(mx, __shfl_xor(mx, 32));

        const float newm = fmaxf(m_s, mx);
        const float fac = exp2f(m_s - newm);
        float rs = 0.f;
#pragma unroll
        for (int j = 0; j < 8; ++j) {
#pragma unroll
            for (int r = 0; r < 4; ++r) {
                const float p = exp2f(s[j][r] - newm);
                s[j][r] = p;
                rs += p;
            }
        }
        rs += __shfl_xor(rs, 16);
        rs += __shfl_xor(rs, 32);
        l_s = l_s * fac + rs;
        m_s = newm;
#pragma unroll
        for (int jj = 0; jj < 4; ++jj) ctxT[jj] *= fac;

        // P -> LDS (row = this lane's q, packed half4 per j)
#pragma unroll
        for (int j = 0; j < 8; ++j) {
            half4 t;
            t.x = (f16)s[j][0]; t.y = (f16)s[j][1]; t.z = (f16)s[j][2]; t.w = (f16)s[j][3];
            *(half4*)&Ps[w][cl][j * 16 + g * 4] = t;
        }

        half8 bp[4];
#pragma unroll
        for (int ks = 0; ks < 4; ++ks)
            bp[ks] = *(const half8*)&Ps[w][cl][ks * 32 + g * 8];

        // ctx^T = V^T P^T (swapped): contraction kv=128 -> 4 k-segments
#pragma unroll
        for (int ks = 0; ks < 4; ++ks) {
#pragma unroll
            for (int jj = 0; jj < 4; ++jj) {
                const half8 av = *(const half8*)&Vs[jj * 16 + cl][ks * 32 + g * 8];
                ctxT[jj] = __builtin_amdgcn_mfma_f32_16x16x32_f16(av, bp[ks], ctxT[jj], 0, 0, 0);
            }
        }

        __syncthreads();               // all waves done reading Ks/Vs
        if (kt < nfull) { WRITET(); }  // commit prefetched tile
        __syncthreads();
    }
#undef LOADT
#undef WRITET

    // epilogue: O f16, merged heads. lane: q = qlane, d = jj*16 + g*4 + r
    const int b = bh >> 3;
    const int h = bh & (HH - 1);
    const float inv = 1.0f / l_s;
#pragma unroll
    for (int jj = 0; jj < 4; ++jj) {
        half4 o;
        o.x = (f16)(ctxT[jj][0] * inv);
        o.y = (f16)(ctxT[jj][1] * inv);
        o.z = (f16)(ctxT[jj][2] * inv);
        o.w = (f16)(ctxT[jj][3] * inv);
        *(half4*)&Of[((size_t)b * SS + qlane) * DD + h * HD + jj * 16 + g * 4] = o;
    }
}

// ---------------------------------------------------------------------------
// K3: O-projection + residual. Tile 128M x 64N, BK=64, 256 thr = 4 waves
// (2x2, each 64x32). A = Of f16, B = wof f16. grid (8, 32). fp32 out.
// ---------------------------------------------------------------------------
__global__ __launch_bounds__(256) void gemm_o(const f16* __restrict__ A,
                                              const f16* __restrict__ W,
                                              const float* __restrict__ bias,
                                              const float* __restrict__ resid,
                                              float* __restrict__ out) {
    __shared__ f16 As[128][72];
    __shared__ f16 Bs[64][72];

    const int tid = threadIdx.x;
    const int lane = tid & 63;
    const int wid = tid >> 6;
    const int wr = wid >> 1, wc = wid & 1;
    const int cl = lane & 15, g = lane >> 4;
    const int m0 = blockIdx.y * 128, n0 = blockIdx.x * 64;

    f32x4 acc[4][2] = {};

    for (int k0 = 0; k0 < DD; k0 += 64) {
        {
            const int srow = tid >> 1, scp = tid & 1;
#pragma unroll
            for (int p = 0; p < 4; ++p)
                *(half8*)&As[srow][scp * 32 + p * 8] =
                    *(const half8*)(A + (size_t)(m0 + srow) * DD + k0 + scp * 32 + p * 8);
            const int brow = tid >> 2, bcq = tid & 3;
#pragma unroll
            for (int p = 0; p < 2; ++p)
                *(half8*)&Bs[brow][bcq * 16 + p * 8] =
                    *(const half8*)(W + (size_t)(n0 + brow) * DD + k0 + bcq * 16 + p * 8);
        }
        __syncthreads();

#pragma unroll
        for (int ks = 0; ks < 2; ++ks) {
            half8 a[4], b[2];
#pragma unroll
            for (int i = 0; i < 4; ++i)
                a[i] = *(const half8*)&As[wr * 64 + i * 16 + cl][ks * 32 + g * 8];
#pragma unroll
            for (int j = 0; j < 2; ++j)
                b[j] = *(const half8*)&Bs[wc * 32 + j * 16 + cl][ks * 32 + g * 8];
#pragma unroll
            for (int i = 0; i < 4; ++i)
#pragma unroll
                for (int j = 0; j < 2; ++j)
                    acc[i][j] = __builtin_amdgcn_mfma_f32_16x16x32_f16(a[i], b[j], acc[i][j], 0, 0, 0);
        }
        __syncthreads();
    }

#pragma unroll
    for (int j = 0; j < 2; ++j) {
        const int n = n0 + wc * 32 + j * 16 + cl;
        const float bn = bias[n];
#pragma unroll
        for (int i = 0; i < 4; ++i) {
#pragma unroll
            for (int r = 0; r < 4; ++r) {
                const int m = m0 + wr * 64 + i * 16 + g * 4 + r;
                const size_t idx = (size_t)m * DD + n;
                out[idx] = acc[i][j][r] + bn + resid[idx];
            }
        }
    }
}

// ---------------------------------------------------------------------------
// K4: LayerNorm, one wave per row of 512, fp32.
// ---------------------------------------------------------------------------
__global__ __launch_bounds__(256) void ln_k(const float* __restrict__ X,
                                            const float* __restrict__ gamma,
                                            const float* __restrict__ beta,
                                            float* __restrict__ out) {
    const int row = blockIdx.x * 4 + (threadIdx.x >> 6);
    const int lane = threadIdx.x & 63;
    const float* x = X + (size_t)row * DD;

    const float4 v0 = *reinterpret_cast<const float4*>(x + lane * 4);
    const float4 v1 = *reinterpret_cast<const float4*>(x + 256 + lane * 4);

    float sum = v0.x + v0.y + v0.z + v0.w + v1.x + v1.y + v1.z + v1.w;
#pragma unroll
    for (int off = 1; off < 64; off <<= 1) sum += __shfl_xor(sum, off, 64);
    const float mu = sum * (1.0f / DD);

    const float d0[8] = {v0.x - mu, v0.y - mu, v0.z - mu, v0.w - mu,
                         v1.x - mu, v1.y - mu, v1.z - mu, v1.w - mu};
    float vs = 0.f;
#pragma unroll
    for (int t = 0; t < 8; ++t) vs += d0[t] * d0[t];
#pragma unroll
    for (int off = 1; off < 64; off <<= 1) vs += __shfl_xor(vs, off, 64);
    const float rstd = rsqrtf(vs * (1.0f / DD) + LN_EPS);

    const float4 g0 = *reinterpret_cast<const float4*>(gamma + lane * 4);
    const float4 g1 = *reinterpret_cast<const float4*>(gamma + 256 + lane * 4);
    const float4 b0 = *reinterpret_cast<const float4*>(beta + lane * 4);
    const float4 b1 = *reinterpret_cast<const float4*>(beta + 256 + lane * 4);

    float4 o0, o1;
    o0.x = g0.x * d0[0] * rstd + b0.x;
    o0.y = g0.y * d0[1] * rstd + b0.y;
    o0.z = g0.z * d0[2] * rstd + b0.z;
    o0.w = g0.w * d0[3] * rstd + b0.w;
    o1.x = g1.x * d0[4] * rstd + b1.x;
    o1.y = g1.y * d0[5] * rstd + b1.y;
    o1.z = g1.z * d0[6] * rstd + b1.z;
    o1.w = g1.w * d0[7] * rstd + b1.w;

    *reinterpret_cast<float4*>(out + (size_t)row * DD + lane * 4) = o0;
    *reinterpret_cast<float4*>(out + (size_t)row * DD + 256 + lane * 4) = o1;
}

// ---------------------------------------------------------------------------
extern "C" void kernel_launch(void* const* d_in, const int* in_sizes, int n_in,
                              void* d_out, int out_size, void* d_ws, size_t ws_size,
                              hipStream_t stream) {
    const float* q     = (const float*)d_in[0];
    const float* k     = (const float*)d_in[1];
    const float* v     = (const float*)d_in[2];
    const float* wq    = (const float*)d_in[3];
    const float* bq    = (const float*)d_in[4];
    const float* wk    = (const float*)d_in[5];
    const float* bk    = (const float*)d_in[6];
    const float* wv    = (const float*)d_in[7];
    const float* bv    = (const float*)d_in[8];
    const float* wo    = (const float*)d_in[9];
    const float* bo    = (const float*)d_in[10];
    const float* gamma = (const float*)d_in[11];
    const float* beta  = (const float*)d_in[12];
    // d_in[13] = causal mask — structure known, not read.

    // ws layout (peak 18 MB):
    //   0-4: Qh f16 | 4-8: Kh f16 | 8-12: Vt f16 [B,H,HD,S] | 12-16: Of f16
    //   16-18: wqf/wkf/wvf/wof f16 (512KB each)
    //   X fp32 aliases 0-8 (Qh/Kh dead after flash)
    char* ws = (char*)d_ws;
    const size_t MB = 1u << 20;
    f16*   Qh  = (f16*)(ws);
    f16*   Kh  = (f16*)(ws + 4 * MB);
    f16*   Vt  = (f16*)(ws + 8 * MB);
    f16*   Of  = (f16*)(ws + 12 * MB);
    f16*   wqf = (f16*)(ws + 16 * MB);
    f16*   wkf = (f16*)(ws + 16 * MB + 512 * 1024);
    f16*   wvf = (f16*)(ws + 17 * MB);
    f16*   wof = (f16*)(ws + 17 * MB + 512 * 1024);
    float* X   = (float*)(ws);

    cvt_w<<<256, 256, 0, stream>>>(wq, wk, wv, wo, wqf, wkf, wvf, wof);

    gemm_qkv<<<dim3(4, 32, 3), 256, 0, stream>>>(
        q, k, v, wqf, wkf, wvf, bq, bk, bv, Qh, Kh, Vt);

    flash_f16<<<dim3(SS / 64, BB * HH), 256, 0, stream>>>(Qh, Kh, Vt, Of);

    gemm_o<<<dim3(8, 32), 256, 0, stream>>>(Of, wof, bo, q, X);

    ln_k<<<(BB * SS) / 4, 256, 0, stream>>>(X, gamma, beta, (float*)d_out);
}